// Round 8
// baseline (551.596 us; speedup 1.0000x reference)
//
#include <hip/hip_runtime.h>
#include <math.h>

#define N_COLS 2048   // N
#define N_ROWS 128    // n
#define KW     32     // W columns (m=30 + p=2)
#define WST    36     // LDS row stride for W (floats)
#define PST    20     // LDS row stride for panel (floats; 16B-aligned rows)

// ---------------- panel factorization: one wave, registers + __shfl broadcast ----------------
// Panel = 16 cols (global 16p..16p+15) x 128 rows in P (row stride PST), y implicit col.
// LDL raw columns: step k: inv=1/P[k][k]; for j>k: P[i][j] -= P[i][k]*inv*P[k][j] (i>k).
// Lane l owns rows l and l+64. p is RUNTIME (uniform); k/j loops compile-time.
static __device__ __forceinline__ void factor_panel(
    const int p, const int l, float* __restrict__ P, float* __restrict__ yL,
    float* __restrict__ invd, float& ld, float& yb) {
  float pr0[16], pr1[16];
#pragma unroll
  for (int qd = 0; qd < 4; ++qd) {
    const float4 v0 = *(const float4*)&P[l * PST + 4 * qd];
    const float4 v1 = *(const float4*)&P[(l + 64) * PST + 4 * qd];
    pr0[4 * qd + 0] = v0.x; pr0[4 * qd + 1] = v0.y; pr0[4 * qd + 2] = v0.z; pr0[4 * qd + 3] = v0.w;
    pr1[4 * qd + 0] = v1.x; pr1[4 * qd + 1] = v1.y; pr1[4 * qd + 2] = v1.z; pr1[4 * qd + 3] = v1.w;
  }
  float py0 = yL[l], py1 = yL[l + 64];
  const int pbase = p << 4;
#pragma unroll
  for (int k = 0; k < 16; ++k) {
    const int prow = pbase + k;      // runtime uniform
    const int olane = prow & 63;
    const bool hi = prow >= 64;      // runtime uniform -> cndmask select
    const float dk = __shfl(hi ? pr1[k] : pr0[k], olane, 64);
    const float yk = __shfl(hi ? py1 : py0, olane, 64);
    const float inv = __builtin_amdgcn_rcpf(dk);
    if (l == 0) { ld += 0.5f * __logf(dk); yb += yk * yk * inv; invd[k] = inv; }
    const float f0 = (l > prow) ? pr0[k] * inv : 0.0f;
    const float f1 = (l + 64 > prow) ? pr1[k] * inv : 0.0f;
#pragma unroll
    for (int j = k + 1; j < 16; ++j) {
      const float rk = __shfl(hi ? pr1[j] : pr0[j], olane, 64);
      pr0[j] = fmaf(-f0, rk, pr0[j]);
      pr1[j] = fmaf(-f1, rk, pr1[j]);
    }
    py0 = fmaf(-f0, yk, py0);
    py1 = fmaf(-f1, yk, py1);
  }
#pragma unroll
  for (int qd = 0; qd < 4; ++qd) {
    *(float4*)&P[l * PST + 4 * qd] =
        make_float4(pr0[4 * qd + 0], pr0[4 * qd + 1], pr0[4 * qd + 2], pr0[4 * qd + 3]);
    *(float4*)&P[(l + 64) * PST + 4 * qd] =
        make_float4(pr1[4 * qd + 0], pr1[4 * qd + 1], pr1[4 * qd + 2], pr1[4 * qd + 3]);
  }
  yL[l] = py0;
  yL[l + 64] = py1;
}

// ---------------- main kernel: one block (1024 threads) per b ----------------
// Thread (r,s): r=t&31, s=t>>5 owns G[r+32a][s+32c], a<4, c<4 -> acc[4][4] (16 regs).
// Deliberately tiny per-thread state: rounds 1-7 showed the allocator spills
// any design needing >~56 VGPRs regardless of launch bounds.
__global__ __launch_bounds__(1024) void chol_main(
    const float* __restrict__ Y, const float* __restrict__ X,
    const float* __restrict__ theta, const int* __restrict__ NNmax,
    const int* __restrict__ mPtr, const int mMax, float* __restrict__ out) {
  // union: Wl (128x36 = 4608 f) overlaps the two panel buffers (2x 128x20 = 5120 f)
  __shared__ __align__(16) float uMem[5120];
  __shared__ float yL[N_ROWS];
  __shared__ float swL[N_ROWS];
  __shared__ __align__(16) float invd[16];
  __shared__ float smaskL[KW];
  __shared__ int nnL[KW];
  __shared__ int nzflag;
  float* const Wl = uMem;
  float* const P0 = uMem;
  float* const P1 = uMem + 2560;

  const int b = blockIdx.x;
  const int t = threadIdx.x;
  const int r = t & 31;
  const int s = t >> 5;    // 0..31

  // ---- per-block scalars ----
  const float logs = -__logf((float)(b + 1));
  const float nug = fmaxf(__expf(theta[0] + theta[1] * logs) - 1e-5f, 0.0f) + 1e-5f;
  const float sigma = __expf(theta[3] + theta[4] * logs);
  const float sig2 = sigma * sigma;
  const float invNug = 1.0f / nug;
  const float invL2 = __expf(-2.0f * theta[5]) * (1.0f / 3.0f);
  int m = *mPtr; if (m > 30) m = 30;

  if (t == 0) nzflag = 0;
  if (t < KW) {
    nnL[t] = (t < m) ? NNmax[b * mMax + t] : 0;
    smaskL[t] = (t < m && t < b) ? __expf(0.5f * (float)(t + 1) * theta[2]) : 0.0f;
  }
  __syncthreads();

  // ---- fill W (128 x 32) in LDS: thread fills 4 cols of one row ----
  {
    const int i0 = t & 127;
    const int jb = t >> 7;   // 0..7
    const float sx0 = __expf(theta[6] + theta[8] * logs);
    const float sx1 = __expf(theta[7] + theta[9] * logs);
#pragma unroll
    for (int qq = 0; qq < 4; ++qq) {
      const int j = jb + 8 * qq;
      float v;
      if (j < m) {
        v = Y[i0 * N_COLS + nnL[j]] * smaskL[j];
      } else if (j < m + 2) {
        const int kc = j - m;
        v = X[(i0 * N_COLS + b) * 2 + kc] * ((kc == 0) ? sx0 : sx1);
      } else {
        v = 0.0f;
      }
      Wl[i0 * WST + j] = v;
    }
  }
  if (t < N_ROWS) {
    const float2 xv = ((const float2*)X)[t * N_COLS + b];
    if (xv.x != 0.0f || xv.y != 0.0f) atomicOr(&nzflag, 1);
    yL[t] = Y[t * N_COLS + b];
  }
  __syncthreads();
  if (nzflag == 0 && t < N_ROWS) {  // xz: zero the X part of W
    Wl[t * WST + m] = 0.0f;
    Wl[t * WST + m + 1] = 0.0f;
  }
  __syncthreads();

  // ---- Gram: acc[a][c] = W[i,:].W[j,:], i=r+32a, j=s+32c ----
  float acc[4][4];
#pragma unroll
  for (int a = 0; a < 4; ++a)
#pragma unroll
    for (int c = 0; c < 4; ++c) acc[a][c] = 0.0f;

#pragma unroll 1
  for (int kk = 0; kk < KW; kk += 4) {
    float4 wc[4];
#pragma unroll
    for (int c = 0; c < 4; ++c)
      wc[c] = *(const float4*)&Wl[(s + 32 * c) * WST + kk];
#pragma unroll
    for (int a = 0; a < 4; ++a) {
      const float4 wa = *(const float4*)&Wl[(r + 32 * a) * WST + kk];
#pragma unroll
      for (int c = 0; c < 4; ++c) {
        float v = acc[a][c];
        v = fmaf(wa.x, wc[c].x, v);
        v = fmaf(wa.y, wc[c].y, v);
        v = fmaf(wa.z, wc[c].z, v);
        v = fmaf(wa.w, wc[c].w, v);
        acc[a][c] = v;
      }
    }
  }

  // diag (row sum-of-squares): i==j iff r==s && a==c
  if (r == s) {
#pragma unroll
    for (int a = 0; a < 4; ++a) swL[r + 32 * a] = acc[a][a];
  }
  __syncthreads();

  // ---- transform dot -> G = I + (dot + matern*sig2)/nug ----
  // a-loop not unrolled: caps concurrent transcendental chains at 4.
  if (b != 0) {
    float swc[4];
#pragma unroll
    for (int c = 0; c < 4; ++c) swc[c] = swL[s + 32 * c];
#pragma unroll 1
    for (int a = 0; a < 4; ++a) {
      const float swa = swL[r + 32 * a];
#pragma unroll
      for (int c = 0; c < 4; ++c) {
        const float d = acc[a][c];
        float r2 = (swa + swc[c] - 2.0f * d) * invL2;
        r2 = fmaxf(r2, 0.0f);
        const float cc = sqrtf(3.0f * r2);
        const float mat = (1.0f + cc) * __expf(-cc);
        float g = fmaf(mat, sig2, d) * invNug;
        if (r == s && a == c) g += 1.0f;
        acc[a][c] = g;
      }
    }
  } else {
#pragma unroll
    for (int a = 0; a < 4; ++a)
#pragma unroll
      for (int c = 0; c < 4; ++c)
        acc[a][c] = (r == s && a == c) ? 1.0f : 0.0f;
  }

  // export panel 0 (cols 0..15): threads with s<16 own them in c-group 0
  if (s < 16) {
#pragma unroll
    for (int a = 0; a < 4; ++a) P0[(r + 32 * a) * PST + s] = acc[a][0];
  }

  // ---- 8 panels (runtime loop): factor (wave 0) + rank-16 trailing update ----
  float ld = 0.0f, yb = 0.0f;
  for (int p = 0; p < 8; ++p) {
    float* const Pc = (p & 1) ? P1 : P0;
    float* const Pn = (p & 1) ? P0 : P1;
    __syncthreads();                       // panel p columns complete in Pc
    if (t < 64) {
      // park acc[2..4) (8 floats) in Pn[0..512) (dead data) during the factor
#pragma unroll
      for (int a = 2; a < 4; ++a)
        *(float4*)&Pn[t * 8 + 4 * (a - 2)] =
            make_float4(acc[a][0], acc[a][1], acc[a][2], acc[a][3]);
      factor_panel(p, t, Pc, yL, invd, ld, yb);
#pragma unroll
      for (int a = 2; a < 4; ++a) {
        const float4 v = *(const float4*)&Pn[t * 8 + 4 * (a - 2)];
        acc[a][0] = v.x; acc[a][1] = v.y; acc[a][2] = v.z; acc[a][3] = v.w;
      }
    }
    __syncthreads();                       // factored panel + invd + yL visible
    const int q = p + 1;
    if (q < 8) {
      const int b16q = 16 * q;
#pragma unroll 1
      for (int kk = 0; kk < 16; kk += 4) {
        const float4 iv4 = *(const float4*)&invd[kk];
        float4 rc4[4];
#pragma unroll
        for (int c = 0; c < 4; ++c)
          if (32 * c + 31 >= b16q)          // uniform; dead c-groups skipped
            rc4[c] = *(const float4*)&Pc[(s + 32 * c) * PST + kk];
#pragma unroll
        for (int a = 0; a < 4; ++a) {
          if (32 * a + 31 >= b16q) {        // uniform; dead a-groups skipped
            float4 ra = *(const float4*)&Pc[(r + 32 * a) * PST + kk];
            ra.x *= iv4.x; ra.y *= iv4.y; ra.z *= iv4.z; ra.w *= iv4.w;
#pragma unroll
            for (int c = 0; c < 4; ++c) {
              if (32 * c + 31 >= b16q) {
                float v = acc[a][c];
                v = fmaf(-ra.x, rc4[c].x, v);
                v = fmaf(-ra.y, rc4[c].y, v);
                v = fmaf(-ra.z, rc4[c].z, v);
                v = fmaf(-ra.w, rc4[c].w, v);
                acc[a][c] = v;
              }
            }
          }
        }
      }
      // export next panel (cols 16q..16q+15): threads with s-half == q&1, c-group q>>1
      if ((s >> 4) == (q & 1)) {
        const int cq = q >> 1;
#pragma unroll
        for (int a = 0; a < 4; ++a) {
          if (32 * a + 31 >= b16q) {
            const float v = (cq == 0) ? acc[a][0]
                          : (cq == 1) ? acc[a][1]
                          : (cq == 2) ? acc[a][2] : acc[a][3];
            Pn[(r + 32 * a) * PST + (s & 15)] = v;
          }
        }
      }
    }
  }

  // ---- final reduction (thread 0 == lane 0 of wave 0, holds ld/yb) ----
  if (t == 0) {
    const float alpha = 2.0625f;          // (1/NUG_MULT^2)+2
    const float alphaPost = alpha + 64.0f;
    const float beta = 1.0625f * nug;     // nug*(alpha-1)
    const float betaPost = beta + 0.5f * yb;
    const float loglik = -ld + alpha * __logf(beta) - alphaPost * __logf(betaPost)
                       + lgammaf(alphaPost) - lgammaf(alpha);
    atomicAdd(out, -loglik);
  }
}

// ---------------- host launch ----------------
extern "C" void kernel_launch(void* const* d_in, const int* in_sizes, int n_in,
                              void* d_out, int out_size, void* d_ws, size_t ws_size,
                              hipStream_t stream) {
  const float* Y = (const float*)d_in[0];
  const float* X = (const float*)d_in[1];
  const float* theta = (const float*)d_in[2];
  const int* NNmax = (const int*)d_in[3];
  const int* mPtr = (const int*)d_in[4];
  float* out = (float*)d_out;
  const int mMax = in_sizes[3] / N_COLS;  // 64

  hipMemsetAsync(out, 0, sizeof(float) * out_size, stream);
  chol_main<<<N_COLS, 1024, 0, stream>>>(Y, X, theta, NNmax, mPtr, mMax, out);
}

// Round 9
// 445.474 us; speedup vs baseline: 1.2382x; 1.2382x over previous
//
#include <hip/hip_runtime.h>
#include <math.h>

#define N_COLS 2048   // N
#define N_ROWS 128    // n
#define KW     32     // W columns (m=30 + p=2)
#define WST    36     // LDS row stride for W (floats)
#define PST    20     // LDS row stride for panel (floats; 16B-aligned rows)

// ---------------- panel factorization: one wave, registers + __shfl broadcast ----------------
// Panel = 16 cols (global 16p..16p+15) x 128 rows in P (row stride PST), y implicit col.
// LDL raw columns: step k: inv=1/P[k][k]; for j>k: P[i][j] -= P[i][k]*inv*P[k][j] (i>k).
// Lane l owns rows l and l+64. Pivot row broadcast per-element via __shfl.
static __device__ __forceinline__ void factor_panel(
    const int p, const int l, float* __restrict__ P, float* __restrict__ yL,
    float* __restrict__ invd, float& ld, float& yb) {
  float pr0[16], pr1[16];
#pragma unroll
  for (int qd = 0; qd < 4; ++qd) {
    const float4 v0 = *(const float4*)&P[l * PST + 4 * qd];
    const float4 v1 = *(const float4*)&P[(l + 64) * PST + 4 * qd];
    pr0[4 * qd + 0] = v0.x; pr0[4 * qd + 1] = v0.y; pr0[4 * qd + 2] = v0.z; pr0[4 * qd + 3] = v0.w;
    pr1[4 * qd + 0] = v1.x; pr1[4 * qd + 1] = v1.y; pr1[4 * qd + 2] = v1.z; pr1[4 * qd + 3] = v1.w;
  }
  float py0 = yL[l], py1 = yL[l + 64];
  const int pbase = p << 4;
#pragma unroll
  for (int k = 0; k < 16; ++k) {
    const int prow = pbase + k;
    const int olane = prow & 63;
    const bool hi = prow >= 64;      // compile-time after caller's p-unroll
    const float dk = __shfl(hi ? pr1[k] : pr0[k], olane, 64);
    const float yk = __shfl(hi ? py1 : py0, olane, 64);
    const float inv = __builtin_amdgcn_rcpf(dk);
    if (l == 0) { ld += 0.5f * __logf(dk); yb += yk * yk * inv; invd[k] = inv; }
    const float f0 = (l > prow) ? pr0[k] * inv : 0.0f;
    const float f1 = (l + 64 > prow) ? pr1[k] * inv : 0.0f;
#pragma unroll
    for (int j = k + 1; j < 16; ++j) {
      const float rk = __shfl(hi ? pr1[j] : pr0[j], olane, 64);
      pr0[j] = fmaf(-f0, rk, pr0[j]);
      pr1[j] = fmaf(-f1, rk, pr1[j]);
    }
    py0 = fmaf(-f0, yk, py0);
    py1 = fmaf(-f1, yk, py1);
  }
#pragma unroll
  for (int qd = 0; qd < 4; ++qd) {
    *(float4*)&P[l * PST + 4 * qd] =
        make_float4(pr0[4 * qd + 0], pr0[4 * qd + 1], pr0[4 * qd + 2], pr0[4 * qd + 3]);
    *(float4*)&P[(l + 64) * PST + 4 * qd] =
        make_float4(pr1[4 * qd + 0], pr1[4 * qd + 1], pr1[4 * qd + 2], pr1[4 * qd + 3]);
  }
  yL[l] = py0;
  yL[l + 64] = py1;
}

// ---------------- main kernel: one block (256 threads) per b ----------------
// Thread (ti,tj), ti=t&15, tj=t>>4 owns G[ti+16a][tj+16c], a,c<8 -> gr[8][8].
// launch_bounds(256, 1): observed allocator mapping cap = 512/(2*minWaves)
// ((256,2)->128, (256,3)->84, (256,4)->64). minWaves=1 -> cap 256, above the
// ~140-reg demand, so no scratch spill (rounds 1-8 all spilled).
__global__ __launch_bounds__(256, 1) void chol_main(
    const float* __restrict__ Y, const float* __restrict__ X,
    const float* __restrict__ theta, const int* __restrict__ NNmax,
    const int* __restrict__ mPtr, const int mMax, float* __restrict__ out) {
  // union: Wl (128x36 = 4608 f) overlaps the two panel buffers (2x 128x20 = 5120 f)
  __shared__ __align__(16) float uMem[5120];
  __shared__ float yL[N_ROWS];
  __shared__ float swL[N_ROWS];
  __shared__ __align__(16) float invd[16];
  __shared__ float smaskL[KW];
  __shared__ int nnL[KW];
  __shared__ int nzflag;
  float* const Wl = uMem;
  float* const P0 = uMem;
  float* const P1 = uMem + 2560;

  const int b = blockIdx.x;
  const int t = threadIdx.x;
  const int ti = t & 15;
  const int tj = t >> 4;   // 0..15

  // ---- per-block scalars ----
  const float logs = -__logf((float)(b + 1));
  const float nug = fmaxf(__expf(theta[0] + theta[1] * logs) - 1e-5f, 0.0f) + 1e-5f;
  const float sigma = __expf(theta[3] + theta[4] * logs);
  const float sig2 = sigma * sigma;
  const float invNug = 1.0f / nug;
  const float invL2 = __expf(-2.0f * theta[5]) * (1.0f / 3.0f);
  int m = *mPtr; if (m > 30) m = 30;

  if (t == 0) nzflag = 0;
  if (t < KW) {
    nnL[t] = (t < m) ? NNmax[b * mMax + t] : 0;
    smaskL[t] = (t < m && t < b) ? __expf(0.5f * (float)(t + 1) * theta[2]) : 0.0f;
  }
  __syncthreads();

  // ---- fill W (128 x 32) in LDS: each thread fills 16 cols of one row ----
  {
    const int i0 = t & 127;
    const int jb = t >> 7;   // 0..1
    const float sx0 = __expf(theta[6] + theta[8] * logs);
    const float sx1 = __expf(theta[7] + theta[9] * logs);
#pragma unroll
    for (int qq = 0; qq < 16; ++qq) {
      const int j = jb + 2 * qq;
      float v;
      if (j < m) {
        v = Y[i0 * N_COLS + nnL[j]] * smaskL[j];
      } else if (j < m + 2) {
        const int kc = j - m;
        v = X[(i0 * N_COLS + b) * 2 + kc] * ((kc == 0) ? sx0 : sx1);
      } else {
        v = 0.0f;
      }
      Wl[i0 * WST + j] = v;
    }
  }
  if (t < N_ROWS) {
    const float2 xv = ((const float2*)X)[t * N_COLS + b];
    if (xv.x != 0.0f || xv.y != 0.0f) atomicOr(&nzflag, 1);
    yL[t] = Y[t * N_COLS + b];
  }
  __syncthreads();
  if (nzflag == 0 && t < N_ROWS) {  // xz: zero the X part of W
    Wl[t * WST + m] = 0.0f;
    Wl[t * WST + m + 1] = 0.0f;
  }
  __syncthreads();

  // ---- Gram: gr[a][c] = W[i,:].W[j,:], i=ti+16a, j=tj+16c; c tiled by 4 ----
  float gr[8][8];
#pragma unroll
  for (int a = 0; a < 8; ++a)
#pragma unroll
    for (int c = 0; c < 8; ++c) gr[a][c] = 0.0f;

#pragma unroll
  for (int g = 0; g < 2; ++g) {
#pragma unroll 2
    for (int kk = 0; kk < KW; kk += 4) {
      float4 wc[4];
#pragma unroll
      for (int c = 0; c < 4; ++c)
        wc[c] = *(const float4*)&Wl[(tj + 16 * (4 * g + c)) * WST + kk];
#pragma unroll
      for (int a = 0; a < 8; ++a) {
        const float4 wa = *(const float4*)&Wl[(ti + 16 * a) * WST + kk];
#pragma unroll
        for (int c = 0; c < 4; ++c) {
          float v = gr[a][4 * g + c];
          v = fmaf(wa.x, wc[c].x, v);
          v = fmaf(wa.y, wc[c].y, v);
          v = fmaf(wa.z, wc[c].z, v);
          v = fmaf(wa.w, wc[c].w, v);
          gr[a][4 * g + c] = v;
        }
      }
    }
  }

  // diag (row sum-of-squares) to swL
  if (ti == tj) {
#pragma unroll
    for (int a = 0; a < 8; ++a) swL[ti + 16 * a] = gr[a][a];
  }
  __syncthreads();

  // ---- transform dot -> G = I + (dot + matern*sig2)/nug ----
  // a-loop unroll 2: caps concurrent transcendental chains at 16.
  if (b != 0) {
    float swc[8];
#pragma unroll
    for (int c = 0; c < 8; ++c) swc[c] = swL[tj + 16 * c];
#pragma unroll 2
    for (int a = 0; a < 8; ++a) {
      const float swa = swL[ti + 16 * a];
#pragma unroll
      for (int c = 0; c < 8; ++c) {
        const float d = gr[a][c];
        float r2 = (swa + swc[c] - 2.0f * d) * invL2;
        r2 = fmaxf(r2, 0.0f);
        const float cc = sqrtf(3.0f * r2);
        const float mat = (1.0f + cc) * __expf(-cc);
        float g = fmaf(mat, sig2, d) * invNug;
        if (ti + 16 * a == tj + 16 * c) g += 1.0f;
        gr[a][c] = g;
      }
    }
  } else {
#pragma unroll
    for (int a = 0; a < 8; ++a)
#pragma unroll
      for (int c = 0; c < 8; ++c)
        gr[a][c] = (ti + 16 * a == tj + 16 * c) ? 1.0f : 0.0f;
  }

  // export panel 0 (cols 0..15, all 128 rows)
#pragma unroll
  for (int a = 0; a < 8; ++a) P0[(ti + 16 * a) * PST + tj] = gr[a][0];

  // ---- 8 panels (UNROLLED: static gr indexing): factor + rank-16 trailing ----
  float ld = 0.0f, yb = 0.0f;
#pragma unroll
  for (int p = 0; p < 8; ++p) {
    float* const Pc = (p & 1) ? P1 : P0;
    float* const Pn = (p & 1) ? P0 : P1;
    __syncthreads();                       // panel p columns complete in Pc
    if (t < 64) {
      // park gr[a][4..8) (32 floats) in Pn's dead storage during the factor;
      // Pn is next written by the export AFTER the mid barrier.
#pragma unroll
      for (int a = 0; a < 8; ++a)
        *(float4*)&Pn[t * 36 + 4 * a] = make_float4(gr[a][4], gr[a][5], gr[a][6], gr[a][7]);
      factor_panel(p, t, Pc, yL, invd, ld, yb);
#pragma unroll
      for (int a = 0; a < 8; ++a) {
        const float4 v = *(const float4*)&Pn[t * 36 + 4 * a];
        gr[a][4] = v.x; gr[a][5] = v.y; gr[a][6] = v.z; gr[a][7] = v.w;
      }
    }
    __syncthreads();                       // factored panel + invd + yL visible
    if (p < 7) {
      const int q = p + 1;
      // trailing update: c tiled in 4s, kk unroll 2 to bound live set
#pragma unroll
      for (int g = 0; g < 2; ++g) {
        const int clo = (4 * g > q) ? 4 * g : q;   // compile-time after unroll
        if (clo < 4 * g + 4) {
#pragma unroll 2
          for (int kk = 0; kk < 16; kk += 4) {
            const float4 iv4 = *(const float4*)&invd[kk];
            float4 rc4[4];
#pragma unroll
            for (int c = 0; c < 4; ++c)
              if (4 * g + c >= clo)
                rc4[c] = *(const float4*)&Pc[(tj + 16 * (4 * g + c)) * PST + kk];
#pragma unroll
            for (int a = q; a < 8; ++a) {
              float4 ra = *(const float4*)&Pc[(ti + 16 * a) * PST + kk];
              ra.x *= iv4.x; ra.y *= iv4.y; ra.z *= iv4.z; ra.w *= iv4.w;
#pragma unroll
              for (int c = 0; c < 4; ++c) {
                if (4 * g + c >= clo) {
                  float v = gr[a][4 * g + c];
                  v = fmaf(-ra.x, rc4[c].x, v);
                  v = fmaf(-ra.y, rc4[c].y, v);
                  v = fmaf(-ra.z, rc4[c].z, v);
                  v = fmaf(-ra.w, rc4[c].w, v);
                  gr[a][4 * g + c] = v;
                }
              }
            }
          }
        }
      }
      // export next panel (cols 16q..16q+15; only rows >= 16q are read later)
#pragma unroll
      for (int a = q; a < 8; ++a) Pn[(ti + 16 * a) * PST + tj] = gr[a][q];
    }
  }

  // ---- final reduction (thread 0 == lane 0 of wave 0, holds ld/yb) ----
  if (t == 0) {
    const float alpha = 2.0625f;          // (1/NUG_MULT^2)+2
    const float alphaPost = alpha + 64.0f;
    const float beta = 1.0625f * nug;     // nug*(alpha-1)
    const float betaPost = beta + 0.5f * yb;
    const float loglik = -ld + alpha * __logf(beta) - alphaPost * __logf(betaPost)
                       + lgammaf(alphaPost) - lgammaf(alpha);
    atomicAdd(out, -loglik);
  }
}

// ---------------- host launch ----------------
extern "C" void kernel_launch(void* const* d_in, const int* in_sizes, int n_in,
                              void* d_out, int out_size, void* d_ws, size_t ws_size,
                              hipStream_t stream) {
  const float* Y = (const float*)d_in[0];
  const float* X = (const float*)d_in[1];
  const float* theta = (const float*)d_in[2];
  const int* NNmax = (const int*)d_in[3];
  const int* mPtr = (const int*)d_in[4];
  float* out = (float*)d_out;
  const int mMax = in_sizes[3] / N_COLS;  // 64

  hipMemsetAsync(out, 0, sizeof(float) * out_size, stream);
  chol_main<<<N_COLS, 256, 0, stream>>>(Y, X, theta, NNmax, mPtr, mMax, out);
}